// Round 5
// baseline (218.697 us; speedup 1.0000x reference)
//
#include <hip/hip_runtime.h>
#include <hip/hip_bf16.h>

typedef __bf16 bf16_t;
typedef bf16_t bf16x8 __attribute__((ext_vector_type(8)));
typedef float floatx4 __attribute__((ext_vector_type(4)));
typedef float floatx2 __attribute__((ext_vector_type(2)));

#define N_NODES 100000
#define N_EDGES 1000000

// PQ8 row layout (256 B per node): byte b = h*128 + l15*8 + j  holds fp8 of
// column  h*128 + j*16 + l15   (h = half, l15 = 0..15, j = 0..7).
// Edge kernel lane lg reads bytes lg*8..lg*8+7 of a half -> channels j*16+lg,
// identical mapping for p-half and q-half, wabs permuted to match.

// ---------------- kernel 1: prep ----------------
// blocks 0..127: WT[n][k] = Wcat[k][n] bf16  (Wcat[k,n] = n<128 ? W1[k,n] : W1[k+128,n-128])
// block 128: w1 = wd*(1+a)/2 (channel order), wabs_perm[b] = wd(c)*(1-a(c))/2
//            with c = (b&7)*16 + (b>>3);  u1[k]=sum_j W1[k,j]w1[j],
//            u2[k]=sum_j W1[k+128,j]w1[j]; CONST = sum w1*b1 + (b2[1]-b2[0])
__global__ __launch_bounds__(256) void k_prep(const float* __restrict__ W1,
                                              const float* __restrict__ b1,
                                              const float* __restrict__ alpha,
                                              const float* __restrict__ W2,
                                              const float* __restrict__ b2,
                                              bf16_t* __restrict__ WT,
                                              float* __restrict__ wabsp,
                                              float* __restrict__ u1g,
                                              float* __restrict__ u2g,
                                              float* __restrict__ constg) {
    __shared__ float w1L[128];
    int i = blockIdx.x * 256 + threadIdx.x;
    if (i < 32768) {
        int n = i >> 7;
        int k = i & 127;
        float v = (n < 128) ? W1[k * 128 + n] : W1[(k + 128) * 128 + (n - 128)];
        WT[i] = (bf16_t)v;
    }
    if (blockIdx.x == 128) {
        int t = threadIdx.x;
        if (t < 128) {
            float wd = W2[2 * t + 1] - W2[2 * t];
            float al = alpha[t];
            w1L[t] = wd * (1.f + al) * 0.5f;
            int c = (t & 7) * 16 + (t >> 3);          // permuted channel
            float wdc = W2[2 * c + 1] - W2[2 * c];
            wabsp[t] = wdc * (1.f - alpha[c]) * 0.5f;
        }
        __syncthreads();
        if (t < 128) {
            float a1 = 0.f, a2 = 0.f;
            for (int j = 0; j < 128; ++j) {
                a1 = fmaf(W1[t * 128 + j], w1L[j], a1);
                a2 = fmaf(W1[(t + 128) * 128 + j], w1L[j], a2);
            }
            u1g[t] = a1;
            u2g[t] = a2;
        }
        if (t == 0) {
            float c = 0.f;
            for (int j = 0; j < 128; ++j) c = fmaf(w1L[j], b1[j], c);
            *constg = c + (b2[1] - b2[0]);
        }
    }
}

// ---------------- kernel 2: LDS-free GEMM + aux, one wave = 16 rows x 256 cols
__global__ __launch_bounds__(256) void k_gemm(const float* __restrict__ F,     // [100000,128]
                                              const bf16_t* __restrict__ WT,   // [256,128]
                                              const float* __restrict__ b1,
                                              const float* __restrict__ u1g,
                                              const float* __restrict__ u2g,
                                              const int* __restrict__ label,
                                              unsigned char* __restrict__ PQ8,
                                              float4* __restrict__ aux_g) {
    const int lane = threadIdx.x & 63;
    const int wid = blockIdx.x * 4 + (threadIdx.x >> 6);
    const int m0 = wid * 16;
    if (m0 >= N_NODES) return;
    const int l15 = lane & 15, quad = lane >> 4;

    const float4* Fr = (const float4*)(F + (size_t)(m0 + l15) * 128);
    floatx4 acc[16] = {};
    float a1 = 0.f, a2 = 0.f;

#pragma unroll
    for (int s = 0; s < 4; ++s) {
        float4 fa = Fr[s * 8 + quad * 2];
        float4 fb = Fr[s * 8 + quad * 2 + 1];
        const float* u1p = u1g + s * 32 + quad * 8;
        const float* u2p = u2g + s * 32 + quad * 8;
        float fv[8] = {fa.x, fa.y, fa.z, fa.w, fb.x, fb.y, fb.z, fb.w};
#pragma unroll
        for (int j = 0; j < 8; ++j) {
            a1 = fmaf(fv[j], u1p[j], a1);
            a2 = fmaf(fv[j], u2p[j], a2);
        }
        bf16x8 af;
#pragma unroll
        for (int j = 0; j < 8; ++j) af[j] = (bf16_t)fv[j];

#pragma unroll
        for (int g = 0; g < 4; ++g) {
            bf16x8 bf[4];
#pragma unroll
            for (int jj = 0; jj < 4; ++jj)
                bf[jj] = *(const bf16x8*)(WT + (size_t)((g * 4 + jj) * 16 + l15) * 128 + s * 32 + quad * 8);
#pragma unroll
            for (int jj = 0; jj < 4; ++jj)
                acc[g * 4 + jj] = __builtin_amdgcn_mfma_f32_16x16x32_bf16(af, bf[jj], acc[g * 4 + jj], 0, 0, 0);
        }
    }

    // aux: reduce a1/a2 across quads (same l15), store {s1, s2, label}
    a1 += __shfl_xor(a1, 16, 64); a1 += __shfl_xor(a1, 32, 64);
    a2 += __shfl_xor(a2, 16, 64); a2 += __shfl_xor(a2, 32, 64);
    if (quad == 0) {
        int grow = m0 + l15;
        float4 av = {a1, a2, __int_as_float(label[grow]), 0.f};
        aux_g[grow] = av;
    }

    // epilogue: bias (cols<128 only), fp8 pack, fully-coalesced uint2 stores
    float bv[8];
#pragma unroll
    for (int j = 0; j < 8; ++j) bv[j] = b1[j * 16 + l15];
#pragma unroll
    for (int r = 0; r < 4; ++r) {
        int grow = m0 + quad * 4 + r;
        unsigned char* rowp = PQ8 + (size_t)grow * 256 + l15 * 8;
        {   // h = 0 (cols 0..127, +bias)
            unsigned int lo = 0, hi = 0;
            lo = __builtin_amdgcn_cvt_pk_fp8_f32(acc[0][r] + bv[0], acc[1][r] + bv[1], lo, false);
            lo = __builtin_amdgcn_cvt_pk_fp8_f32(acc[2][r] + bv[2], acc[3][r] + bv[3], lo, true);
            hi = __builtin_amdgcn_cvt_pk_fp8_f32(acc[4][r] + bv[4], acc[5][r] + bv[5], hi, false);
            hi = __builtin_amdgcn_cvt_pk_fp8_f32(acc[6][r] + bv[6], acc[7][r] + bv[7], hi, true);
            uint2 pk; pk.x = lo; pk.y = hi;
            *(uint2*)(rowp) = pk;
        }
        {   // h = 1 (cols 128..255, no bias)
            unsigned int lo = 0, hi = 0;
            lo = __builtin_amdgcn_cvt_pk_fp8_f32(acc[8][r],  acc[9][r],  lo, false);
            lo = __builtin_amdgcn_cvt_pk_fp8_f32(acc[10][r], acc[11][r], lo, true);
            hi = __builtin_amdgcn_cvt_pk_fp8_f32(acc[12][r], acc[13][r], hi, false);
            hi = __builtin_amdgcn_cvt_pk_fp8_f32(acc[14][r], acc[15][r], hi, true);
            uint2 pk; pk.x = lo; pk.y = hi;
            *(uint2*)(rowp + 128) = pk;
        }
    }
}

// ---------------- kernel 3: per-edge loss, 16 lanes/edge, 8-edge ILP -------
__global__ __launch_bounds__(256) void k_edge_loss(const unsigned char* __restrict__ PQ8,
                                                   const float4* __restrict__ aux,
                                                   const float* __restrict__ wabsp,
                                                   const float* __restrict__ constg,
                                                   const int* __restrict__ row,
                                                   const int* __restrict__ col,
                                                   float* __restrict__ out) {
    const int lg = threadIdx.x & 15;
    const int group = (blockIdx.x * blockDim.x + threadIdx.x) >> 4;
    const int ng = (gridDim.x * blockDim.x) >> 4;
    const int ch = lg * 8;

    float wabs[8];
#pragma unroll
    for (int j = 0; j < 8; ++j) wabs[j] = wabsp[ch + j];
    const float CB = *constg;

    float acc = 0.f;
    for (int e = group; e < N_EDGES; e += 8 * ng) {
        int r[8], c[8];
#pragma unroll
        for (int k = 0; k < 8; ++k) {
            int ee = e + k * ng;
            int es = (ee < N_EDGES) ? ee : e;
            r[k] = row[es]; c[k] = col[es];
        }
        uint2 p[8], q[8];
#pragma unroll
        for (int k = 0; k < 8; ++k) {
            p[k] = *(const uint2*)(PQ8 + (size_t)r[k] * 256 + ch);
            q[k] = *(const uint2*)(PQ8 + (size_t)c[k] * 256 + 128 + ch);
        }
        // per-lane aux: lanes 0-7 take edge lg's row-aux, lanes 8-15 edge (lg-8)'s col-aux
        int ee2 = e + (lg & 7) * ng;
        int es2 = (ee2 < N_EDGES) ? ee2 : e;
        const int* ibase = (lg < 8) ? row : col;
        float4 a = aux[ibase[es2]];

        float sab[8] = {0.f, 0.f, 0.f, 0.f, 0.f, 0.f, 0.f, 0.f};
#pragma unroll
        for (int k = 0; k < 8; ++k) {
            floatx2 p01 = __builtin_amdgcn_cvt_pk_f32_fp8((int)p[k].x, false);
            floatx2 p23 = __builtin_amdgcn_cvt_pk_f32_fp8((int)p[k].x, true);
            floatx2 p45 = __builtin_amdgcn_cvt_pk_f32_fp8((int)p[k].y, false);
            floatx2 p67 = __builtin_amdgcn_cvt_pk_f32_fp8((int)p[k].y, true);
            floatx2 q01 = __builtin_amdgcn_cvt_pk_f32_fp8((int)q[k].x, false);
            floatx2 q23 = __builtin_amdgcn_cvt_pk_f32_fp8((int)q[k].x, true);
            floatx2 q45 = __builtin_amdgcn_cvt_pk_f32_fp8((int)q[k].y, false);
            floatx2 q67 = __builtin_amdgcn_cvt_pk_f32_fp8((int)q[k].y, true);
            floatx2 h01 = p01 + q01;
            floatx2 h23 = p23 + q23;
            floatx2 h45 = p45 + q45;
            floatx2 h67 = p67 + q67;
            float s = sab[k];
            s = fmaf(fabsf(h01[0]), wabs[0], s);
            s = fmaf(fabsf(h01[1]), wabs[1], s);
            s = fmaf(fabsf(h23[0]), wabs[2], s);
            s = fmaf(fabsf(h23[1]), wabs[3], s);
            s = fmaf(fabsf(h45[0]), wabs[4], s);
            s = fmaf(fabsf(h45[1]), wabs[5], s);
            s = fmaf(fabsf(h67[0]), wabs[6], s);
            s = fmaf(fabsf(h67[1]), wabs[7], s);
            sab[k] = s;
        }
#pragma unroll
        for (int m = 8; m >= 1; m >>= 1) {
#pragma unroll
            for (int k = 0; k < 8; ++k) sab[k] += __shfl_xor(sab[k], m, 16);
        }
        // lanes 0-7 finish edge lg in parallel
        float s2o = __shfl(a.y, (lg + 8) & 15, 16);
        float lzc = __shfl(a.z, (lg + 8) & 15, 16);
        float mysab = sab[0];
#pragma unroll
        for (int k = 1; k < 8; ++k) mysab = (lg == k) ? sab[k] : mysab;
        float D = a.x + s2o + CB + mysab;
        float sgn = (__float_as_int(a.z) == __float_as_int(lzc)) ? -D : D;
        float loss = fmaxf(sgn, 0.f) + __logf(1.f + __expf(-fabsf(sgn)));
        bool vld = (lg < 8) && (e + lg * ng < N_EDGES);
        acc += vld ? loss : 0.f;
    }
#pragma unroll
    for (int m = 32; m >= 1; m >>= 1) acc += __shfl_xor(acc, m, 64);
    __shared__ float sdata[4];
    int lane = threadIdx.x & 63;
    int wv = threadIdx.x >> 6;
    if (lane == 0) sdata[wv] = acc;
    __syncthreads();
    if (threadIdx.x == 0) {
        float s = (sdata[0] + sdata[1]) + (sdata[2] + sdata[3]);
        atomicAdd(out, s * (1.f / (float)N_EDGES));
    }
}

extern "C" void kernel_launch(void* const* d_in, const int* in_sizes, int n_in,
                              void* d_out, int out_size, void* d_ws, size_t ws_size,
                              hipStream_t stream) {
    const float* feature = (const float*)d_in[0];   // [100000,128]
    const float* W1      = (const float*)d_in[1];   // [256,128]
    const float* b1      = (const float*)d_in[2];   // [128]
    const float* alpha   = (const float*)d_in[3];   // [128]
    const float* W2      = (const float*)d_in[4];   // [128,2]
    const float* b2      = (const float*)d_in[5];   // [2]
    const int*   row     = (const int*)d_in[6];     // [1M]
    const int*   col     = (const int*)d_in[7];     // [1M]
    const int*   label   = (const int*)d_in[8];     // [100000]
    float* out = (float*)d_out;

    char* ws = (char*)d_ws;
    unsigned char* PQ8 = (unsigned char*)(ws);      // 25,600,000 B
    float4* aux  = (float4*)(ws + 25600000);        // 1,600,000 B
    bf16_t* WT   = (bf16_t*)(ws + 27200000);        // 65,536 B
    float* wabsp = (float*)(ws + 27265536);         // 512 B
    float* u1g   = (float*)(ws + 27266048);         // 512 B
    float* u2g   = (float*)(ws + 27266560);         // 512 B
    float* constg= (float*)(ws + 27267072);         // 4 B

    hipMemsetAsync(d_out, 0, sizeof(float), stream);

    k_prep<<<129, 256, 0, stream>>>(W1, b1, alpha, W2, b2, WT, wabsp, u1g, u2g, constg);
    k_gemm<<<1563, 256, 0, stream>>>(feature, WT, b1, u1g, u2g, label, PQ8, aux);
    k_edge_loss<<<2048, 256, 0, stream>>>(PQ8, aux, wabsp, constg, row, col, out);
}